// Round 8
// baseline (188.190 us; speedup 1.0000x reference)
//
#include <hip/hip_runtime.h>
#include <hip/hip_fp8.h>
#include <stdint.h>

#define DIMS 512
#define NQ 784
#define QPAD 832           // 13 tiles of 64 query columns
#define NTILE 13
#define RESCORE 32
#define CSTR 528           // LDS/qb8p bytes per query column (512 + 16 pad)
#define TBYTES (64 * CSTR) // 33792 per tile image

typedef float f32x4 __attribute__((ext_vector_type(4)));
typedef long  l2v  __attribute__((ext_vector_type(2)));

__device__ __forceinline__ unsigned umn(unsigned a, unsigned b) { return a < b ? a : b; }
__device__ __forceinline__ unsigned umx(unsigned a, unsigned b) { return a > b ? a : b; }

__device__ __forceinline__ unsigned pk4(float a, float b, float c, float d) {
#if __has_builtin(__builtin_amdgcn_cvt_pk_fp8_f32)
    int v = 0;
    v = __builtin_amdgcn_cvt_pk_fp8_f32(a, b, v, false);
    v = __builtin_amdgcn_cvt_pk_fp8_f32(c, d, v, true);
    return (unsigned)v;
#else
    __hip_fp8_e4m3 x(a), y(b), z(c), w(d);
    return (unsigned)x.__x | ((unsigned)y.__x << 8) | ((unsigned)z.__x << 16) | ((unsigned)w.__x << 24);
#endif
}

// fp32 query -> fp8 e4m3 written as the exact LDS tile image:
// tile-major, column stride 528B, granule (8 dims) at kg*128 + ks*8.
__global__ __launch_bounds__(256) void prep_query(const float* __restrict__ q,
                                                  char* __restrict__ qb8p) {
    int gid = blockIdx.x * 256 + threadIdx.x;   // 832 cols * 64 granules
    int col = gid >> 6;
    int g = gid & 63;                           // ks = g>>2, kg = g&3
    float4 a = make_float4(0.f, 0.f, 0.f, 0.f), b = a;
    if (col < NQ) {
        a = *(const float4*)(q + (size_t)col * DIMS + g * 8);
        b = *(const float4*)(q + (size_t)col * DIMS + g * 8 + 4);
    }
    uint2 o;
    o.x = pk4(a.x, a.y, a.z, a.w);
    o.y = pk4(b.x, b.y, b.z, b.w);
    int tile = col >> 6, cin = col & 63;
    *(uint2*)(qb8p + (size_t)tile * TBYTES + cin * CSTR + (g & 3) * 128 + (g >> 2) * 8) = o;
}

// 512 WGs = 256 row-groups x 2 query-halves; twins share an XCD for L2 reuse
// of the bank rows. 4 waves/WG, 64 bank rows per wave as fp8 A-fragments in
// registers (128 VGPR). Query tiles stream through double-buffered LDS.
// Per-wave in-register top-2 per (col, 32-row half), exact rescore later.
__global__ __launch_bounds__(256, 2) void score_kernel(
    const float* __restrict__ bank,
    const char* __restrict__ qb8p,
    uint2* __restrict__ cand)
{
    __shared__ __align__(16) char bt[2][TBYTES];   // 67584 B
    __shared__ float m2s[256];

    const int bid = blockIdx.x;
    const int wg2 = (bid & 7) | ((bid >> 4) << 3);  // row-group [0,256)
    const int qh  = (bid >> 3) & 1;                 // query half
    const int t0 = qh ? 7 : 0;
    const int t1 = qh ? NTILE : 7;
    const int t = threadIdx.x;
    const int v = t >> 6;             // wave 0..3
    const int lane = t & 63;
    const int lo = lane & 15;
    const int kg = lane >> 4;         // 0..3

#define STAGE(BUF, TILE)                                                                   \
    do {                                                                                   \
        _Pragma("unroll")                                                                  \
        for (int j = 0; j < 8; ++j) {                                                      \
            const int ch = v * 8 + j;                                                      \
            const char* src = qb8p + (size_t)(TILE) * TBYTES + ch * 1024 + lane * 16;      \
            __builtin_amdgcn_global_load_lds(                                              \
                (const __attribute__((address_space(1))) unsigned*)src,                    \
                (__attribute__((address_space(3))) unsigned*)(&bt[0][0] + (BUF) * TBYTES + ch * 1024), \
                16, 0, 0);                                                                 \
        }                                                                                  \
        if (v == 0) {                                                                      \
            const char* src = qb8p + (size_t)(TILE) * TBYTES + 32768 + lane * 16;          \
            __builtin_amdgcn_global_load_lds(                                              \
                (const __attribute__((address_space(1))) unsigned*)src,                    \
                (__attribute__((address_space(3))) unsigned*)(&bt[0][0] + (BUF) * TBYTES + 32768), \
                16, 0, 0);                                                                 \
        }                                                                                  \
    } while (0)

    STAGE(0, t0);   // overlaps the A-load below

    // ---- A-load: 64 bank rows/wave, fp32 -> fp8 fragments + exact m2 ----
    long areg[4][16];
    #pragma unroll
    for (int m = 0; m < 4; ++m) {
        const float* rp = bank + ((size_t)(wg2 * 256 + v * 64 + m * 16 + lo)) * DIMS + kg * 8;
        float ss = 0.f;
        #pragma unroll
        for (int ks = 0; ks < 16; ++ks) {
            float4 x = *(const float4*)(rp + ks * 32);
            float4 y = *(const float4*)(rp + ks * 32 + 4);
            ss += x.x * x.x + x.y * x.y + x.z * x.z + x.w * x.w;
            ss += y.x * y.x + y.y * y.y + y.z * y.z + y.w * y.w;
            unsigned l32 = pk4(x.x, x.y, x.z, x.w);
            unsigned h32 = pk4(y.x, y.y, y.z, y.w);
            areg[m][ks] = (long)(((unsigned long long)h32 << 32) | l32);
        }
        ss += __shfl_xor(ss, 16);
        ss += __shfl_xor(ss, 32);
        if (lane < 16) m2s[v * 64 + m * 16 + lane] = ss;
    }

    asm volatile("s_waitcnt vmcnt(0)" ::: "memory");
    __syncthreads();

    // acc seed: -(512 + m2/2); packed score = -acc > 0 always
    f32x4 seed[4];
    #pragma unroll
    for (int m = 0; m < 4; ++m)
        #pragma unroll
        for (int j = 0; j < 4; ++j)
            seed[m][j] = -(512.0f + 0.5f * m2s[v * 64 + m * 16 + kg * 4 + j]);

    // single B base; buf/ntp/ks offsets fold into immediates
    const char* pB = &bt[0][0] + lo * CSTR + kg * 128;

#define KSLOOP(ACC, PBT, NTP)                                                              \
    do {                                                                                   \
        __builtin_amdgcn_s_setprio(1);                                                     \
        _Pragma("unroll")                                                                  \
        for (int ks2 = 0; ks2 < 8; ++ks2) {                                                \
            const int off = (NTP) * (32 * CSTR) + ks2 * 16;                                \
            l2v B0 = *(const l2v*)((PBT) + off);                                           \
            l2v B1 = *(const l2v*)((PBT) + off + 16 * CSTR);                               \
            _Pragma("unroll")                                                              \
            for (int m = 0; m < 4; ++m) {                                                  \
                ACC[m][0] = __builtin_amdgcn_mfma_f32_16x16x32_fp8_fp8(areg[m][2 * ks2], B0[0], ACC[m][0], 0, 0, 0); \
                ACC[m][1] = __builtin_amdgcn_mfma_f32_16x16x32_fp8_fp8(areg[m][2 * ks2], B1[0], ACC[m][1], 0, 0, 0); \
            }                                                                              \
            _Pragma("unroll")                                                              \
            for (int m = 0; m < 4; ++m) {                                                  \
                ACC[m][0] = __builtin_amdgcn_mfma_f32_16x16x32_fp8_fp8(areg[m][2 * ks2 + 1], B0[1], ACC[m][0], 0, 0, 0); \
                ACC[m][1] = __builtin_amdgcn_mfma_f32_16x16x32_fp8_fp8(areg[m][2 * ks2 + 1], B1[1], ACC[m][1], 0, 0, 0); \
            }                                                                              \
        }                                                                                  \
        __builtin_amdgcn_s_setprio(0);                                                     \
    } while (0)

    // top-2 per (16-col group n, 32-row half H) -> packed uint2
#define SEL2(ACC, TILE, NTP)                                                               \
    do {                                                                                   \
        _Pragma("unroll")                                                                  \
        for (int n = 0; n < 2; ++n)                                                        \
            _Pragma("unroll")                                                              \
            for (int H = 0; H < 2; ++H) {                                                  \
                unsigned v1 = 0xFFFFFFFFu, v2 = 0xFFFFFFFFu;                               \
                _Pragma("unroll")                                                          \
                for (int mm = 0; mm < 2; ++mm)                                             \
                    _Pragma("unroll")                                                      \
                    for (int j = 0; j < 4; ++j) {                                          \
                        unsigned u = ((__float_as_uint(ACC[2 * H + mm][n][j]) ^ 0x80000000u) & ~31u) \
                                     | (unsigned)(mm * 16 + kg * 4 + j);                   \
                        unsigned mx = umx(v1, u);                                          \
                        v1 = umn(v1, u);                                                   \
                        v2 = umn(v2, mx);                                                  \
                    }                                                                      \
                _Pragma("unroll")                                                          \
                for (int off = 16; off <= 32; off <<= 1) {                                 \
                    unsigned o1 = (unsigned)__shfl_xor((int)v1, off);                      \
                    unsigned o2 = (unsigned)__shfl_xor((int)v2, off);                      \
                    unsigned mx = umx(v1, o1);                                             \
                    v1 = umn(v1, o1);                                                      \
                    v2 = umn(umn(v2, o2), mx);                                             \
                }                                                                          \
                int col = (TILE) * 64 + (NTP) * 32 + n * 16 + lo;                          \
                if (lane < 16 && col < NQ)                                                 \
                    cand[(size_t)(wg2 * 8 + v * 2 + H) * QPAD + col] = make_uint2(v1, v2); \
            }                                                                              \
    } while (0)

    #pragma unroll 1
    for (int tile = t0; tile < t1; ++tile) {
        const int buf = (tile - t0) & 1;
        if (tile + 1 < t1) STAGE(buf ^ 1, tile + 1);
        const char* pBt = pB + buf * TBYTES;
        f32x4 acc[4][2];
        #pragma unroll
        for (int m = 0; m < 4; ++m) { acc[m][0] = seed[m]; acc[m][1] = seed[m]; }
        KSLOOP(acc, pBt, 0);
        SEL2(acc, tile, 0);
        #pragma unroll
        for (int m = 0; m < 4; ++m) { acc[m][0] = seed[m]; acc[m][1] = seed[m]; }
        KSLOOP(acc, pBt, 1);
        SEL2(acc, tile, 1);
        asm volatile("s_waitcnt vmcnt(0)" ::: "memory");
        __syncthreads();
    }
#undef SEL2
#undef KSLOOP
#undef STAGE
}

// One wave per query row: per-lane sorted top-8 over 64 packed values ->
// 32 ballot-min extractions -> exact fp64 rescore (2 lanes/candidate) ->
// top-4 -> neighbor mean.
__global__ __launch_bounds__(256) void merge_kernel(
    const float* __restrict__ query, const float* __restrict__ bank,
    const uint2* __restrict__ cand, float* __restrict__ nm)
{
    __shared__ double d2s[4][32];
    __shared__ int    cis[4][32];

    const int wv = threadIdx.x >> 6, lane = threadIdx.x & 63;
    const int row = blockIdx.x * 4 + wv;

    unsigned s0 = ~0u, s1 = ~0u, s2 = ~0u, s3 = ~0u;
    unsigned s4 = ~0u, s5 = ~0u, s6 = ~0u, s7 = ~0u;

#define INS(U)                                        \
    do {                                              \
        unsigned tt = (U), nv;                        \
        nv = umn(s0, tt); tt = umx(s0, tt); s0 = nv;  \
        nv = umn(s1, tt); tt = umx(s1, tt); s1 = nv;  \
        nv = umn(s2, tt); tt = umx(s2, tt); s2 = nv;  \
        nv = umn(s3, tt); tt = umx(s3, tt); s3 = nv;  \
        nv = umn(s4, tt); tt = umx(s4, tt); s4 = nv;  \
        nv = umn(s5, tt); tt = umx(s5, tt); s5 = nv;  \
        nv = umn(s6, tt); tt = umx(s6, tt); s6 = nv;  \
        s7 = umn(s7, tt);                             \
    } while (0)

    // lane owns groups [lane*32, +32); re-encode group-in-lane into bits 5..9
    #pragma unroll 4
    for (int j = 0; j < 32; ++j) {
        uint2 e = cand[((size_t)(lane * 32 + j)) * QPAD + row];
        unsigned jb = (unsigned)(j << 5);
        INS((e.x & ~0x3E0u) | jb);
        INS((e.y & ~0x3E0u) | jb);
    }
#undef INS

    const int myC = lane & 31;
    int myCand = 0;
    #pragma unroll
    for (int it = 0; it < RESCORE; ++it) {
        unsigned gm = s0;
        #pragma unroll
        for (int off = 1; off < 64; off <<= 1)
            gm = umn(gm, (unsigned)__shfl_xor((int)gm, off));
        unsigned long long bal = __ballot(s0 == gm);
        int wl = __ffsll((long long)bal) - 1;
        int ci = (wl * 32 + (int)((gm >> 5) & 31u)) * 32 + (int)(gm & 31u);
        myCand = (it == myC) ? ci : myCand;
        if (lane == wl) { s0 = s1; s1 = s2; s2 = s3; s3 = s4; s4 = s5; s5 = s6; s6 = s7; s7 = ~0u; }
    }

    // exact fp64 rescore: lanes l and l+32 split candidate (lane&31)'s dims
    const float* qr = query + (size_t)row * DIMS + (lane >> 5) * 256;
    const float* mr = bank + (size_t)myCand * DIMS + (lane >> 5) * 256;
    double s = 0.0;
    #pragma unroll 8
    for (int i = 0; i < 64; ++i) {
        float4 a = *(const float4*)(qr + i * 4);
        float4 b = *(const float4*)(mr + i * 4);
        double d;
        d = (double)a.x - (double)b.x; s += d * d;
        d = (double)a.y - (double)b.y; s += d * d;
        d = (double)a.z - (double)b.z; s += d * d;
        d = (double)a.w - (double)b.w; s += d * d;
    }
    s += __shfl_xor(s, 32);
    if (lane < 32) { d2s[wv][lane] = s; cis[wv][lane] = myCand; }
    __syncthreads();

    // top-4 of 32 (computed redundantly per lane), index tie-break
    int sel0 = 0, sel1 = 0, sel2 = 0, sel3 = 0;
    unsigned used = 0;
    #pragma unroll
    for (int k = 0; k < 4; ++k) {
        double bv = 1e300; int bidx = 0x7FFFFFFF; int bc = 0;
        for (int c = 0; c < 32; ++c) {
            bool live = !((used >> c) & 1u);
            double dv = d2s[wv][c];
            int cv = cis[wv][c];
            if (live && (dv < bv || (dv == bv && cv < bidx))) { bv = dv; bidx = cv; bc = c; }
        }
        used |= 1u << bc;
        if (k == 0) sel0 = bidx; else if (k == 1) sel1 = bidx;
        else if (k == 2) sel2 = bidx; else sel3 = bidx;
    }

    const float* r0 = bank + (size_t)sel0 * DIMS + lane * 8;
    const float* r1 = bank + (size_t)sel1 * DIMS + lane * 8;
    const float* r2 = bank + (size_t)sel2 * DIMS + lane * 8;
    const float* r3 = bank + (size_t)sel3 * DIMS + lane * 8;
    float* dst = nm + (size_t)row * DIMS + lane * 8;
    #pragma unroll
    for (int h = 0; h < 2; ++h) {
        float4 a = *(const float4*)(r0 + h * 4);
        float4 b = *(const float4*)(r1 + h * 4);
        float4 c = *(const float4*)(r2 + h * 4);
        float4 d = *(const float4*)(r3 + h * 4);
        float4 o;
        o.x = 0.25f * (a.x + b.x + c.x + d.x);
        o.y = 0.25f * (a.y + b.y + c.y + d.y);
        o.z = 0.25f * (a.z + b.z + c.z + d.z);
        o.w = 0.25f * (a.w + b.w + c.w + d.w);
        *(float4*)(dst + h * 4) = o;
    }
}

__global__ __launch_bounds__(256) void conv_kernel(
    const float* __restrict__ query, const float* __restrict__ nm,
    const float* __restrict__ fw, const float* __restrict__ fb,
    float* __restrict__ out)
{
    __shared__ float red[256];
    int pix = blockIdx.x, t = threadIdx.x;
    int i = pix / 28, j = pix % 28;
    float acc = 0.f;
    for (int c = t; c < 1024; c += 256) {
        const float* wrow = fw + c * 9;
        for (int di = 0; di < 3; ++di) {
            int h = i + di - 1;
            if (h < 0 || h >= 28) continue;
            for (int dj = 0; dj < 3; ++dj) {
                int w = j + dj - 1;
                if (w < 0 || w >= 28) continue;
                int n = h * 28 + w;
                float x = (c < 512) ? query[(size_t)n * 512 + c]
                                    : nm[(size_t)n * 512 + (c - 512)];
                acc += x * wrow[di * 3 + dj];
            }
        }
    }
    red[t] = acc;
    __syncthreads();
    for (int s = 128; s; s >>= 1) {
        if (t < s) red[t] += red[t + s];
        __syncthreads();
    }
    if (t == 0) out[pix] = red[0] + fb[0];
}

extern "C" void kernel_launch(void* const* d_in, const int* in_sizes, int n_in,
                              void* d_out, int out_size, void* d_ws, size_t ws_size,
                              hipStream_t stream)
{
    const float* query = (const float*)d_in[0];
    const float* bank  = (const float*)d_in[1];
    const float* fw    = (const float*)d_in[2];
    const float* fb    = (const float*)d_in[3];
    float* out = (float*)d_out;

    char* ws = (char*)d_ws;
    char*  qb8p = ws;                                      // 13*33792     =   439296 B
    uint2* cand = (uint2*)(ws + 439296);                   // 2048*832*8   = 13631488 B
    float* nm   = (float*)(ws + 439296 + 13631488);        // 784*512*4    =  1605632 B

    prep_query<<<208, 256, 0, stream>>>(query, qb8p);
    score_kernel<<<512, 256, 0, stream>>>(bank, qb8p, cand);
    merge_kernel<<<NQ / 4, 256, 0, stream>>>(query, bank, cand, nm);
    conv_kernel<<<NQ, 256, 0, stream>>>(query, nm, fw, fb, out);
}

// Round 9
// 187.994 us; speedup vs baseline: 1.0010x; 1.0010x over previous
//
#include <hip/hip_runtime.h>
#include <hip/hip_fp8.h>
#include <stdint.h>

#define DIMS 512
#define NQ 784
#define QPAD 832           // 13 tiles of 64 query columns
#define NTILE 13
#define RESCORE 32
#define CSTR 528           // LDS/qb8p bytes per query column (512 + 16 pad)
#define TBYTES (64 * CSTR) // 33792 per tile image

typedef float f32x4 __attribute__((ext_vector_type(4)));
typedef long  l2v  __attribute__((ext_vector_type(2)));

__device__ __forceinline__ unsigned umn(unsigned a, unsigned b) { return a < b ? a : b; }
__device__ __forceinline__ unsigned umx(unsigned a, unsigned b) { return a > b ? a : b; }

__device__ __forceinline__ unsigned pk4(float a, float b, float c, float d) {
#if __has_builtin(__builtin_amdgcn_cvt_pk_fp8_f32)
    int v = 0;
    v = __builtin_amdgcn_cvt_pk_fp8_f32(a, b, v, false);
    v = __builtin_amdgcn_cvt_pk_fp8_f32(c, d, v, true);
    return (unsigned)v;
#else
    __hip_fp8_e4m3 x(a), y(b), z(c), w(d);
    return (unsigned)x.__x | ((unsigned)y.__x << 8) | ((unsigned)z.__x << 16) | ((unsigned)w.__x << 24);
#endif
}

// fp32 query -> fp8 e4m3 written as the exact LDS tile image:
// tile-major, column stride 528B, granule (8 dims) at kg*128 + ks*8.
__global__ __launch_bounds__(256) void prep_query(const float* __restrict__ q,
                                                  char* __restrict__ qb8p) {
    int gid = blockIdx.x * 256 + threadIdx.x;   // 832 cols * 64 granules
    int col = gid >> 6;
    int g = gid & 63;                           // ks = g>>2, kg = g&3
    float4 a = make_float4(0.f, 0.f, 0.f, 0.f), b = a;
    if (col < NQ) {
        a = *(const float4*)(q + (size_t)col * DIMS + g * 8);
        b = *(const float4*)(q + (size_t)col * DIMS + g * 8 + 4);
    }
    uint2 o;
    o.x = pk4(a.x, a.y, a.z, a.w);
    o.y = pk4(b.x, b.y, b.z, b.w);
    int tile = col >> 6, cin = col & 63;
    *(uint2*)(qb8p + (size_t)tile * TBYTES + cin * CSTR + (g & 3) * 128 + (g >> 2) * 8) = o;
}

// 512 WGs = 256 row-groups x 2 query-halves; twins share an XCD for L2 reuse
// of the bank rows. 4 waves/WG, 64 bank rows per wave as fp8 A-fragments in
// registers (128 VGPR). Query tiles stream through double-buffered LDS.
// Per-wave in-register top-2 per (col, 32-row half), exact rescore later.
__global__ __launch_bounds__(256, 2) void score_kernel(
    const float* __restrict__ bank,
    const char* __restrict__ qb8p,
    uint2* __restrict__ cand)
{
    __shared__ __align__(16) char bt[2][TBYTES];   // 67584 B
    __shared__ float m2s[256];

    const int bid = blockIdx.x;
    const int wg2 = (bid & 7) | ((bid >> 4) << 3);  // row-group [0,256)
    const int qh  = (bid >> 3) & 1;                 // query half
    const int t0 = qh ? 7 : 0;
    const int t1 = qh ? NTILE : 7;
    const int t = threadIdx.x;
    const int v = t >> 6;             // wave 0..3
    const int lane = t & 63;
    const int lo = lane & 15;
    const int kg = lane >> 4;         // 0..3

#define STAGE(BUF, TILE)                                                                   \
    do {                                                                                   \
        _Pragma("unroll")                                                                  \
        for (int j = 0; j < 8; ++j) {                                                      \
            const int ch = v * 8 + j;                                                      \
            const char* src = qb8p + (size_t)(TILE) * TBYTES + ch * 1024 + lane * 16;      \
            __builtin_amdgcn_global_load_lds(                                              \
                (const __attribute__((address_space(1))) unsigned*)src,                    \
                (__attribute__((address_space(3))) unsigned*)(&bt[0][0] + (BUF) * TBYTES + ch * 1024), \
                16, 0, 0);                                                                 \
        }                                                                                  \
        if (v == 0) {                                                                      \
            const char* src = qb8p + (size_t)(TILE) * TBYTES + 32768 + lane * 16;          \
            __builtin_amdgcn_global_load_lds(                                              \
                (const __attribute__((address_space(1))) unsigned*)src,                    \
                (__attribute__((address_space(3))) unsigned*)(&bt[0][0] + (BUF) * TBYTES + 32768), \
                16, 0, 0);                                                                 \
        }                                                                                  \
    } while (0)

    STAGE(0, t0);   // overlaps the A-load below

    // ---- A-load: 64 bank rows/wave, fp32 -> fp8 fragments + exact m2 ----
    long areg[4][16];
    #pragma unroll
    for (int m = 0; m < 4; ++m) {
        const float* rp = bank + ((size_t)(wg2 * 256 + v * 64 + m * 16 + lo)) * DIMS + kg * 8;
        float ss = 0.f;
        #pragma unroll
        for (int ks = 0; ks < 16; ++ks) {
            float4 x = *(const float4*)(rp + ks * 32);
            float4 y = *(const float4*)(rp + ks * 32 + 4);
            ss += x.x * x.x + x.y * x.y + x.z * x.z + x.w * x.w;
            ss += y.x * y.x + y.y * y.y + y.z * y.z + y.w * y.w;
            unsigned l32 = pk4(x.x, x.y, x.z, x.w);
            unsigned h32 = pk4(y.x, y.y, y.z, y.w);
            areg[m][ks] = (long)(((unsigned long long)h32 << 32) | l32);
        }
        ss += __shfl_xor(ss, 16);
        ss += __shfl_xor(ss, 32);
        if (lane < 16) m2s[v * 64 + m * 16 + lane] = ss;
    }

    asm volatile("s_waitcnt vmcnt(0)" ::: "memory");
    __syncthreads();

    // acc seed: -(512 + m2/2); packed score = -acc > 0 always
    f32x4 seed[4];
    #pragma unroll
    for (int m = 0; m < 4; ++m)
        #pragma unroll
        for (int j = 0; j < 4; ++j)
            seed[m][j] = -(512.0f + 0.5f * m2s[v * 64 + m * 16 + kg * 4 + j]);

    // single B base; buf/ntp/ks offsets fold into immediates
    const char* pB = &bt[0][0] + lo * CSTR + kg * 128;

#define KSLOOP(ACC, PBT, NTP)                                                              \
    do {                                                                                   \
        __builtin_amdgcn_s_setprio(1);                                                     \
        _Pragma("unroll")                                                                  \
        for (int ks2 = 0; ks2 < 8; ++ks2) {                                                \
            const int off = (NTP) * (32 * CSTR) + ks2 * 16;                                \
            l2v B0 = *(const l2v*)((PBT) + off);                                           \
            l2v B1 = *(const l2v*)((PBT) + off + 16 * CSTR);                               \
            _Pragma("unroll")                                                              \
            for (int m = 0; m < 4; ++m) {                                                  \
                ACC[m][0] = __builtin_amdgcn_mfma_f32_16x16x32_fp8_fp8(areg[m][2 * ks2], B0[0], ACC[m][0], 0, 0, 0); \
                ACC[m][1] = __builtin_amdgcn_mfma_f32_16x16x32_fp8_fp8(areg[m][2 * ks2], B1[0], ACC[m][1], 0, 0, 0); \
            }                                                                              \
            _Pragma("unroll")                                                              \
            for (int m = 0; m < 4; ++m) {                                                  \
                ACC[m][0] = __builtin_amdgcn_mfma_f32_16x16x32_fp8_fp8(areg[m][2 * ks2 + 1], B0[1], ACC[m][0], 0, 0, 0); \
                ACC[m][1] = __builtin_amdgcn_mfma_f32_16x16x32_fp8_fp8(areg[m][2 * ks2 + 1], B1[1], ACC[m][1], 0, 0, 0); \
            }                                                                              \
        }                                                                                  \
        __builtin_amdgcn_s_setprio(0);                                                     \
    } while (0)

    // top-2 per (16-col group n, 32-row half H) -> packed uint2
#define SEL2(ACC, TILE, NTP)                                                               \
    do {                                                                                   \
        _Pragma("unroll")                                                                  \
        for (int n = 0; n < 2; ++n)                                                        \
            _Pragma("unroll")                                                              \
            for (int H = 0; H < 2; ++H) {                                                  \
                unsigned v1 = 0xFFFFFFFFu, v2 = 0xFFFFFFFFu;                               \
                _Pragma("unroll")                                                          \
                for (int mm = 0; mm < 2; ++mm)                                             \
                    _Pragma("unroll")                                                      \
                    for (int j = 0; j < 4; ++j) {                                          \
                        unsigned u = ((__float_as_uint(ACC[2 * H + mm][n][j]) ^ 0x80000000u) & ~31u) \
                                     | (unsigned)(mm * 16 + kg * 4 + j);                   \
                        unsigned mx = umx(v1, u);                                          \
                        v1 = umn(v1, u);                                                   \
                        v2 = umn(v2, mx);                                                  \
                    }                                                                      \
                _Pragma("unroll")                                                          \
                for (int off = 16; off <= 32; off <<= 1) {                                 \
                    unsigned o1 = (unsigned)__shfl_xor((int)v1, off);                      \
                    unsigned o2 = (unsigned)__shfl_xor((int)v2, off);                      \
                    unsigned mx = umx(v1, o1);                                             \
                    v1 = umn(v1, o1);                                                      \
                    v2 = umn(umn(v2, o2), mx);                                             \
                }                                                                          \
                int col = (TILE) * 64 + (NTP) * 32 + n * 16 + lo;                          \
                if (lane < 16 && col < NQ)                                                 \
                    cand[(size_t)(wg2 * 8 + v * 2 + H) * QPAD + col] = make_uint2(v1, v2); \
            }                                                                              \
    } while (0)

    #pragma unroll 1
    for (int tile = t0; tile < t1; ++tile) {
        const int buf = (tile - t0) & 1;
        if (tile + 1 < t1) STAGE(buf ^ 1, tile + 1);
        const char* pBt = pB + buf * TBYTES;
        f32x4 acc[4][2];
        #pragma unroll
        for (int m = 0; m < 4; ++m) { acc[m][0] = seed[m]; acc[m][1] = seed[m]; }
        KSLOOP(acc, pBt, 0);
        SEL2(acc, tile, 0);
        #pragma unroll
        for (int m = 0; m < 4; ++m) { acc[m][0] = seed[m]; acc[m][1] = seed[m]; }
        KSLOOP(acc, pBt, 1);
        SEL2(acc, tile, 1);
        asm volatile("s_waitcnt vmcnt(0)" ::: "memory");
        __syncthreads();
    }
#undef SEL2
#undef KSLOOP
#undef STAGE
}

// One wave per query row: per-lane sorted top-8 over 64 packed values ->
// 32 ballot-min extractions -> exact fp64 rescore (2 lanes/candidate) ->
// top-4 -> neighbor mean.
__global__ __launch_bounds__(256) void merge_kernel(
    const float* __restrict__ query, const float* __restrict__ bank,
    const uint2* __restrict__ cand, float* __restrict__ nm)
{
    __shared__ double d2s[4][32];
    __shared__ int    cis[4][32];

    const int wv = threadIdx.x >> 6, lane = threadIdx.x & 63;
    const int row = blockIdx.x * 4 + wv;

    unsigned s0 = ~0u, s1 = ~0u, s2 = ~0u, s3 = ~0u;
    unsigned s4 = ~0u, s5 = ~0u, s6 = ~0u, s7 = ~0u;

#define INS(U)                                        \
    do {                                              \
        unsigned tt = (U), nv;                        \
        nv = umn(s0, tt); tt = umx(s0, tt); s0 = nv;  \
        nv = umn(s1, tt); tt = umx(s1, tt); s1 = nv;  \
        nv = umn(s2, tt); tt = umx(s2, tt); s2 = nv;  \
        nv = umn(s3, tt); tt = umx(s3, tt); s3 = nv;  \
        nv = umn(s4, tt); tt = umx(s4, tt); s4 = nv;  \
        nv = umn(s5, tt); tt = umx(s5, tt); s5 = nv;  \
        nv = umn(s6, tt); tt = umx(s6, tt); s6 = nv;  \
        s7 = umn(s7, tt);                             \
    } while (0)

    // lane owns groups [lane*32, +32); re-encode group-in-lane into bits 5..9
    #pragma unroll 4
    for (int j = 0; j < 32; ++j) {
        uint2 e = cand[((size_t)(lane * 32 + j)) * QPAD + row];
        unsigned jb = (unsigned)(j << 5);
        INS((e.x & ~0x3E0u) | jb);
        INS((e.y & ~0x3E0u) | jb);
    }
#undef INS

    const int myC = lane & 31;
    int myCand = 0;
    #pragma unroll
    for (int it = 0; it < RESCORE; ++it) {
        unsigned gm = s0;
        #pragma unroll
        for (int off = 1; off < 64; off <<= 1)
            gm = umn(gm, (unsigned)__shfl_xor((int)gm, off));
        unsigned long long bal = __ballot(s0 == gm);
        int wl = __ffsll((long long)bal) - 1;
        int ci = (wl * 32 + (int)((gm >> 5) & 31u)) * 32 + (int)(gm & 31u);
        myCand = (it == myC) ? ci : myCand;
        if (lane == wl) { s0 = s1; s1 = s2; s2 = s3; s3 = s4; s4 = s5; s5 = s6; s6 = s7; s7 = ~0u; }
    }

    // exact fp64 rescore: lanes l and l+32 split candidate (lane&31)'s dims
    const float* qr = query + (size_t)row * DIMS + (lane >> 5) * 256;
    const float* mr = bank + (size_t)myCand * DIMS + (lane >> 5) * 256;
    double s = 0.0;
    #pragma unroll 8
    for (int i = 0; i < 64; ++i) {
        float4 a = *(const float4*)(qr + i * 4);
        float4 b = *(const float4*)(mr + i * 4);
        double d;
        d = (double)a.x - (double)b.x; s += d * d;
        d = (double)a.y - (double)b.y; s += d * d;
        d = (double)a.z - (double)b.z; s += d * d;
        d = (double)a.w - (double)b.w; s += d * d;
    }
    s += __shfl_xor(s, 32);
    if (lane < 32) { d2s[wv][lane] = s; cis[wv][lane] = myCand; }
    __syncthreads();

    // top-4 of 32 (computed redundantly per lane), index tie-break
    int sel0 = 0, sel1 = 0, sel2 = 0, sel3 = 0;
    unsigned used = 0;
    #pragma unroll
    for (int k = 0; k < 4; ++k) {
        double bv = 1e300; int bidx = 0x7FFFFFFF; int bc = 0;
        for (int c = 0; c < 32; ++c) {
            bool live = !((used >> c) & 1u);
            double dv = d2s[wv][c];
            int cv = cis[wv][c];
            if (live && (dv < bv || (dv == bv && cv < bidx))) { bv = dv; bidx = cv; bc = c; }
        }
        used |= 1u << bc;
        if (k == 0) sel0 = bidx; else if (k == 1) sel1 = bidx;
        else if (k == 2) sel2 = bidx; else sel3 = bidx;
    }

    const float* r0 = bank + (size_t)sel0 * DIMS + lane * 8;
    const float* r1 = bank + (size_t)sel1 * DIMS + lane * 8;
    const float* r2 = bank + (size_t)sel2 * DIMS + lane * 8;
    const float* r3 = bank + (size_t)sel3 * DIMS + lane * 8;
    float* dst = nm + (size_t)row * DIMS + lane * 8;
    #pragma unroll
    for (int h = 0; h < 2; ++h) {
        float4 a = *(const float4*)(r0 + h * 4);
        float4 b = *(const float4*)(r1 + h * 4);
        float4 c = *(const float4*)(r2 + h * 4);
        float4 d = *(const float4*)(r3 + h * 4);
        float4 o;
        o.x = 0.25f * (a.x + b.x + c.x + d.x);
        o.y = 0.25f * (a.y + b.y + c.y + d.y);
        o.z = 0.25f * (a.z + b.z + c.z + d.z);
        o.w = 0.25f * (a.w + b.w + c.w + d.w);
        *(float4*)(dst + h * 4) = o;
    }
}

__global__ __launch_bounds__(256) void conv_kernel(
    const float* __restrict__ query, const float* __restrict__ nm,
    const float* __restrict__ fw, const float* __restrict__ fb,
    float* __restrict__ out)
{
    __shared__ float red[256];
    int pix = blockIdx.x, t = threadIdx.x;
    int i = pix / 28, j = pix % 28;
    float acc = 0.f;
    for (int c = t; c < 1024; c += 256) {
        const float* wrow = fw + c * 9;
        for (int di = 0; di < 3; ++di) {
            int h = i + di - 1;
            if (h < 0 || h >= 28) continue;
            for (int dj = 0; dj < 3; ++dj) {
                int w = j + dj - 1;
                if (w < 0 || w >= 28) continue;
                int n = h * 28 + w;
                float x = (c < 512) ? query[(size_t)n * 512 + c]
                                    : nm[(size_t)n * 512 + (c - 512)];
                acc += x * wrow[di * 3 + dj];
            }
        }
    }
    red[t] = acc;
    __syncthreads();
    for (int s = 128; s; s >>= 1) {
        if (t < s) red[t] += red[t + s];
        __syncthreads();
    }
    if (t == 0) out[pix] = red[0] + fb[0];
}

extern "C" void kernel_launch(void* const* d_in, const int* in_sizes, int n_in,
                              void* d_out, int out_size, void* d_ws, size_t ws_size,
                              hipStream_t stream)
{
    const float* query = (const float*)d_in[0];
    const float* bank  = (const float*)d_in[1];
    const float* fw    = (const float*)d_in[2];
    const float* fb    = (const float*)d_in[3];
    float* out = (float*)d_out;

    char* ws = (char*)d_ws;
    char*  qb8p = ws;                                      // 13*33792     =   439296 B
    uint2* cand = (uint2*)(ws + 439296);                   // 2048*832*8   = 13631488 B
    float* nm   = (float*)(ws + 439296 + 13631488);        // 784*512*4    =  1605632 B

    prep_query<<<208, 256, 0, stream>>>(query, qb8p);
    score_kernel<<<512, 256, 0, stream>>>(bank, qb8p, cand);
    merge_kernel<<<NQ / 4, 256, 0, stream>>>(query, bank, cand, nm);
    conv_kernel<<<NQ, 256, 0, stream>>>(query, nm, fw, fb, out);
}

// Round 10
// 121.024 us; speedup vs baseline: 1.5550x; 1.5534x over previous
//
#include <hip/hip_runtime.h>
#include <hip/hip_fp8.h>
#include <stdint.h>

#define DIMS 512
#define NQ 784
#define QPAD 832           // 13 tiles of 64 query columns
#define NTILE 13
#define RESCORE 32
#define CSTR 528           // LDS/qb8p bytes per query column (512 + 16 pad)
#define TBYTES (64 * CSTR) // 33792 per tile image (33 chunks of 1024B)

typedef float f32x4 __attribute__((ext_vector_type(4)));
typedef long  l2v  __attribute__((ext_vector_type(2)));

__device__ __forceinline__ unsigned umn(unsigned a, unsigned b) { return a < b ? a : b; }
__device__ __forceinline__ unsigned umx(unsigned a, unsigned b) { return a > b ? a : b; }

__device__ __forceinline__ unsigned pk4(float a, float b, float c, float d) {
#if __has_builtin(__builtin_amdgcn_cvt_pk_fp8_f32)
    int v = 0;
    v = __builtin_amdgcn_cvt_pk_fp8_f32(a, b, v, false);
    v = __builtin_amdgcn_cvt_pk_fp8_f32(c, d, v, true);
    return (unsigned)v;
#else
    __hip_fp8_e4m3 x(a), y(b), z(c), w(d);
    return (unsigned)x.__x | ((unsigned)y.__x << 8) | ((unsigned)z.__x << 16) | ((unsigned)w.__x << 24);
#endif
}

// fp32 query -> fp8 e4m3 written as the exact LDS tile image:
// tile-major, column stride 528B, granule (8 dims) at kg*128 + ks*8.
__global__ __launch_bounds__(256) void prep_query(const float* __restrict__ q,
                                                  char* __restrict__ qb8p) {
    int gid = blockIdx.x * 256 + threadIdx.x;   // 832 cols * 64 granules
    int col = gid >> 6;
    int g = gid & 63;                           // ks = g>>2, kg = g&3
    float4 a = make_float4(0.f, 0.f, 0.f, 0.f), b = a;
    if (col < NQ) {
        a = *(const float4*)(q + (size_t)col * DIMS + g * 8);
        b = *(const float4*)(q + (size_t)col * DIMS + g * 8 + 4);
    }
    uint2 o;
    o.x = pk4(a.x, a.y, a.z, a.w);
    o.y = pk4(b.x, b.y, b.z, b.w);
    int tile = col >> 6, cin = col & 63;
    *(uint2*)(qb8p + (size_t)tile * TBYTES + cin * CSTR + (g & 3) * 128 + (g >> 2) * 8) = o;
}

// 256 WGs x 8 waves (1 WG/CU). Each wave holds 32 bank rows (full K=512)
// as fp8 MFMA A-fragments in registers. Query tiles stream through a
// 4-buffer LDS ring staged by global_load_lds with COUNTED vmcnt (never 0
// in the main loop) + raw s_barrier — loads stay in flight across barriers.
// In-compute register double-buffer (Ba/Bb) hides LDS latency.
__global__ __launch_bounds__(512, 1) void score_kernel(
    const float* __restrict__ bank,
    const char* __restrict__ qb8p,
    uint2* __restrict__ cand)
{
    __shared__ __align__(16) char bt[4][TBYTES];   // 135168 B ring
    __shared__ float m2s[256];

    const int wg = blockIdx.x;        // owns rows wg*256 .. +256
    const int t = threadIdx.x;
    const int v = t >> 6;             // wave 0..7
    const int lane = t & 63;
    const int lo = lane & 15;
    const int kg = lane >> 4;         // 0..3

    // wave v stages chunks 4v..4v+3 (+ chunk 32 for wave 7, issued first)
#define STAGE(BUF, TILE)                                                                   \
    do {                                                                                   \
        if (v == 7) {                                                                      \
            const char* s32 = qb8p + (size_t)(TILE) * TBYTES + 32 * 1024 + lane * 16;      \
            __builtin_amdgcn_global_load_lds(                                              \
                (const __attribute__((address_space(1))) unsigned*)s32,                    \
                (__attribute__((address_space(3))) unsigned*)(&bt[0][0] + (size_t)(BUF) * TBYTES + 32 * 1024), \
                16, 0, 0);                                                                 \
        }                                                                                  \
        _Pragma("unroll")                                                                  \
        for (int j = 0; j < 4; ++j) {                                                      \
            const int ch = v * 4 + j;                                                      \
            const char* src = qb8p + (size_t)(TILE) * TBYTES + ch * 1024 + lane * 16;      \
            __builtin_amdgcn_global_load_lds(                                              \
                (const __attribute__((address_space(1))) unsigned*)src,                    \
                (__attribute__((address_space(3))) unsigned*)(&bt[0][0] + (size_t)(BUF) * TBYTES + ch * 1024), \
                16, 0, 0);                                                                 \
        }                                                                                  \
    } while (0)

    // prologue: 3 tiles in flight before/during the A-load
    STAGE(0, 0);
    STAGE(1, 1);
    STAGE(2, 2);

    // ---- A-load: 32 bank rows/wave, fp32 -> fp8 fragments + exact m2 ----
    long areg[2][16];
    #pragma unroll
    for (int m = 0; m < 2; ++m) {
        const float* rp = bank + ((size_t)(wg * 256 + v * 32 + m * 16 + lo)) * DIMS + kg * 8;
        float ss = 0.f;
        #pragma unroll
        for (int ks = 0; ks < 16; ++ks) {
            float4 x = *(const float4*)(rp + ks * 32);
            float4 y = *(const float4*)(rp + ks * 32 + 4);
            ss += x.x * x.x + x.y * x.y + x.z * x.z + x.w * x.w;
            ss += y.x * y.x + y.y * y.y + y.z * y.z + y.w * y.w;
            unsigned l32 = pk4(x.x, x.y, x.z, x.w);
            unsigned h32 = pk4(y.x, y.y, y.z, y.w);
            areg[m][ks] = (long)(((unsigned long long)h32 << 32) | l32);
        }
        ss += __shfl_xor(ss, 16);
        ss += __shfl_xor(ss, 32);
        if (lane < 16) m2s[v * 32 + m * 16 + lane] = ss;
    }

    // acc seed: -(512 + m2/2); packed score = -acc > 0 always (same-wave LDS)
    f32x4 seed[2];
    #pragma unroll
    for (int m = 0; m < 2; ++m)
        #pragma unroll
        for (int j = 0; j < 4; ++j)
            seed[m][j] = -(512.0f + 0.5f * m2s[v * 32 + m * 16 + kg * 4 + j]);

    const char* pB = &bt[0][0] + lo * CSTR + kg * 128;

#define LOADB(DST, PBT, KS2)                                       \
    do {                                                           \
        DST##0 = *(const l2v*)((PBT) + 0 * 8448 + (KS2) * 16);     \
        DST##1 = *(const l2v*)((PBT) + 1 * 8448 + (KS2) * 16);     \
        DST##2 = *(const l2v*)((PBT) + 2 * 8448 + (KS2) * 16);     \
        DST##3 = *(const l2v*)((PBT) + 3 * 8448 + (KS2) * 16);     \
    } while (0)

#define MFMAS(B, KS2)                                                                            \
    do {                                                                                         \
        acc[0][0] = __builtin_amdgcn_mfma_f32_16x16x32_fp8_fp8(areg[0][2*(KS2)], B##0[0], acc[0][0], 0, 0, 0); \
        acc[1][0] = __builtin_amdgcn_mfma_f32_16x16x32_fp8_fp8(areg[1][2*(KS2)], B##0[0], acc[1][0], 0, 0, 0); \
        acc[0][1] = __builtin_amdgcn_mfma_f32_16x16x32_fp8_fp8(areg[0][2*(KS2)], B##1[0], acc[0][1], 0, 0, 0); \
        acc[1][1] = __builtin_amdgcn_mfma_f32_16x16x32_fp8_fp8(areg[1][2*(KS2)], B##1[0], acc[1][1], 0, 0, 0); \
        acc[0][2] = __builtin_amdgcn_mfma_f32_16x16x32_fp8_fp8(areg[0][2*(KS2)], B##2[0], acc[0][2], 0, 0, 0); \
        acc[1][2] = __builtin_amdgcn_mfma_f32_16x16x32_fp8_fp8(areg[1][2*(KS2)], B##2[0], acc[1][2], 0, 0, 0); \
        acc[0][3] = __builtin_amdgcn_mfma_f32_16x16x32_fp8_fp8(areg[0][2*(KS2)], B##3[0], acc[0][3], 0, 0, 0); \
        acc[1][3] = __builtin_amdgcn_mfma_f32_16x16x32_fp8_fp8(areg[1][2*(KS2)], B##3[0], acc[1][3], 0, 0, 0); \
        acc[0][0] = __builtin_amdgcn_mfma_f32_16x16x32_fp8_fp8(areg[0][2*(KS2)+1], B##0[1], acc[0][0], 0, 0, 0); \
        acc[1][0] = __builtin_amdgcn_mfma_f32_16x16x32_fp8_fp8(areg[1][2*(KS2)+1], B##0[1], acc[1][0], 0, 0, 0); \
        acc[0][1] = __builtin_amdgcn_mfma_f32_16x16x32_fp8_fp8(areg[0][2*(KS2)+1], B##1[1], acc[0][1], 0, 0, 0); \
        acc[1][1] = __builtin_amdgcn_mfma_f32_16x16x32_fp8_fp8(areg[1][2*(KS2)+1], B##1[1], acc[1][1], 0, 0, 0); \
        acc[0][2] = __builtin_amdgcn_mfma_f32_16x16x32_fp8_fp8(areg[0][2*(KS2)+1], B##2[1], acc[0][2], 0, 0, 0); \
        acc[1][2] = __builtin_amdgcn_mfma_f32_16x16x32_fp8_fp8(areg[1][2*(KS2)+1], B##2[1], acc[1][2], 0, 0, 0); \
        acc[0][3] = __builtin_amdgcn_mfma_f32_16x16x32_fp8_fp8(areg[0][2*(KS2)+1], B##3[1], acc[0][3], 0, 0, 0); \
        acc[1][3] = __builtin_amdgcn_mfma_f32_16x16x32_fp8_fp8(areg[1][2*(KS2)+1], B##3[1], acc[1][3], 0, 0, 0); \
    } while (0)

#define SELT(T)                                                                            \
    do {                                                                                   \
        _Pragma("unroll")                                                                  \
        for (int n = 0; n < 4; ++n) {                                                      \
            unsigned v1 = 0xFFFFFFFFu, v2 = 0xFFFFFFFFu;                                   \
            _Pragma("unroll")                                                              \
            for (int m = 0; m < 2; ++m)                                                    \
                _Pragma("unroll")                                                          \
                for (int j = 0; j < 4; ++j) {                                              \
                    unsigned u = ((__float_as_uint(acc[m][n][j]) ^ 0x80000000u) & ~31u)    \
                                 | (unsigned)(m * 16 + kg * 4 + j);                        \
                    unsigned mx = umx(v1, u);                                              \
                    v1 = umn(v1, u);                                                       \
                    v2 = umn(v2, mx);                                                      \
                }                                                                          \
            _Pragma("unroll")                                                              \
            for (int off = 16; off <= 32; off <<= 1) {                                     \
                unsigned o1 = (unsigned)__shfl_xor((int)v1, off);                          \
                unsigned o2 = (unsigned)__shfl_xor((int)v2, off);                          \
                unsigned mx = umx(v1, o1);                                                 \
                v1 = umn(v1, o1);                                                          \
                v2 = umn(umn(v2, o2), mx);                                                 \
            }                                                                              \
            int col = (T) * 64 + n * 16 + lo;                                              \
            if (lane < 16 && col < NQ)                                                     \
                cand[(size_t)(wg * 8 + v) * QPAD + col] = make_uint2(v1, v2);              \
        }                                                                                  \
    } while (0)

#define COMPUTE(T)                                                                         \
    do {                                                                                   \
        const char* pBt = pB + (size_t)((T) & 3) * TBYTES;                                 \
        f32x4 acc[2][4];                                                                   \
        _Pragma("unroll")                                                                  \
        for (int m = 0; m < 2; ++m)                                                        \
            _Pragma("unroll")                                                              \
            for (int n = 0; n < 4; ++n) acc[m][n] = seed[m];                               \
        l2v Ba0, Ba1, Ba2, Ba3, Bb0, Bb1, Bb2, Bb3;                                        \
        LOADB(Ba, pBt, 0);                                                                 \
        __builtin_amdgcn_s_setprio(1);                                                     \
        LOADB(Bb, pBt, 1); MFMAS(Ba, 0);                                                   \
        LOADB(Ba, pBt, 2); MFMAS(Bb, 1);                                                   \
        LOADB(Bb, pBt, 3); MFMAS(Ba, 2);                                                   \
        LOADB(Ba, pBt, 4); MFMAS(Bb, 3);                                                   \
        LOADB(Bb, pBt, 5); MFMAS(Ba, 4);                                                   \
        LOADB(Ba, pBt, 6); MFMAS(Bb, 5);                                                   \
        LOADB(Bb, pBt, 7); MFMAS(Ba, 6);                                                   \
        MFMAS(Bb, 7);                                                                      \
        __builtin_amdgcn_s_setprio(0);                                                     \
        SELT(T);                                                                           \
    } while (0)

#define WAITV(N) asm volatile("s_waitcnt vmcnt(" #N ")" ::: "memory")

    // main loop: counted vmcnt (stage t done, t+1/t+2 in flight), raw barrier
    #pragma unroll 1
    for (int tile = 0; tile < 10; ++tile) {
        WAITV(8);
        __builtin_amdgcn_s_barrier();
        STAGE((tile + 3) & 3, tile + 3);
        COMPUTE(tile);
    }
    WAITV(8);  __builtin_amdgcn_s_barrier();  COMPUTE(10);
    WAITV(4);  __builtin_amdgcn_s_barrier();  COMPUTE(11);
    WAITV(0);  __builtin_amdgcn_s_barrier();  COMPUTE(12);

#undef WAITV
#undef COMPUTE
#undef SELT
#undef MFMAS
#undef LOADB
#undef STAGE
}

// One wave per query row: per-lane sorted top-8 over 64 packed values ->
// 32 ballot-min extractions -> exact fp64 rescore (2 lanes/candidate) ->
// top-4 -> neighbor mean.
__global__ __launch_bounds__(256) void merge_kernel(
    const float* __restrict__ query, const float* __restrict__ bank,
    const uint2* __restrict__ cand, float* __restrict__ nm)
{
    __shared__ double d2s[4][32];
    __shared__ int    cis[4][32];

    const int wv = threadIdx.x >> 6, lane = threadIdx.x & 63;
    const int row = blockIdx.x * 4 + wv;

    unsigned s0 = ~0u, s1 = ~0u, s2 = ~0u, s3 = ~0u;
    unsigned s4 = ~0u, s5 = ~0u, s6 = ~0u, s7 = ~0u;

#define INS(U)                                        \
    do {                                              \
        unsigned tt = (U), nv;                        \
        nv = umn(s0, tt); tt = umx(s0, tt); s0 = nv;  \
        nv = umn(s1, tt); tt = umx(s1, tt); s1 = nv;  \
        nv = umn(s2, tt); tt = umx(s2, tt); s2 = nv;  \
        nv = umn(s3, tt); tt = umx(s3, tt); s3 = nv;  \
        nv = umn(s4, tt); tt = umx(s4, tt); s4 = nv;  \
        nv = umn(s5, tt); tt = umx(s5, tt); s5 = nv;  \
        nv = umn(s6, tt); tt = umx(s6, tt); s6 = nv;  \
        s7 = umn(s7, tt);                             \
    } while (0)

    // lane owns groups [lane*32, +32); re-encode group-in-lane into bits 5..9
    #pragma unroll 4
    for (int j = 0; j < 32; ++j) {
        uint2 e = cand[((size_t)(lane * 32 + j)) * QPAD + row];
        unsigned jb = (unsigned)(j << 5);
        INS((e.x & ~0x3E0u) | jb);
        INS((e.y & ~0x3E0u) | jb);
    }
#undef INS

    const int myC = lane & 31;
    int myCand = 0;
    #pragma unroll
    for (int it = 0; it < RESCORE; ++it) {
        unsigned gm = s0;
        #pragma unroll
        for (int off = 1; off < 64; off <<= 1)
            gm = umn(gm, (unsigned)__shfl_xor((int)gm, off));
        unsigned long long bal = __ballot(s0 == gm);
        int wl = __ffsll((long long)bal) - 1;
        int ci = (wl * 32 + (int)((gm >> 5) & 31u)) * 32 + (int)(gm & 31u);
        myCand = (it == myC) ? ci : myCand;
        if (lane == wl) { s0 = s1; s1 = s2; s2 = s3; s3 = s4; s4 = s5; s5 = s6; s6 = s7; s7 = ~0u; }
    }

    // exact fp64 rescore: lanes l and l+32 split candidate (lane&31)'s dims
    const float* qr = query + (size_t)row * DIMS + (lane >> 5) * 256;
    const float* mr = bank + (size_t)myCand * DIMS + (lane >> 5) * 256;
    double s = 0.0;
    #pragma unroll 8
    for (int i = 0; i < 64; ++i) {
        float4 a = *(const float4*)(qr + i * 4);
        float4 b = *(const float4*)(mr + i * 4);
        double d;
        d = (double)a.x - (double)b.x; s += d * d;
        d = (double)a.y - (double)b.y; s += d * d;
        d = (double)a.z - (double)b.z; s += d * d;
        d = (double)a.w - (double)b.w; s += d * d;
    }
    s += __shfl_xor(s, 32);
    if (lane < 32) { d2s[wv][lane] = s; cis[wv][lane] = myCand; }
    __syncthreads();

    // top-4 of 32 (computed redundantly per lane), index tie-break
    int sel0 = 0, sel1 = 0, sel2 = 0, sel3 = 0;
    unsigned used = 0;
    #pragma unroll
    for (int k = 0; k < 4; ++k) {
        double bv = 1e300; int bidx = 0x7FFFFFFF; int bc = 0;
        for (int c = 0; c < 32; ++c) {
            bool live = !((used >> c) & 1u);
            double dv = d2s[wv][c];
            int cv = cis[wv][c];
            if (live && (dv < bv || (dv == bv && cv < bidx))) { bv = dv; bidx = cv; bc = c; }
        }
        used |= 1u << bc;
        if (k == 0) sel0 = bidx; else if (k == 1) sel1 = bidx;
        else if (k == 2) sel2 = bidx; else sel3 = bidx;
    }

    const float* r0 = bank + (size_t)sel0 * DIMS + lane * 8;
    const float* r1 = bank + (size_t)sel1 * DIMS + lane * 8;
    const float* r2 = bank + (size_t)sel2 * DIMS + lane * 8;
    const float* r3 = bank + (size_t)sel3 * DIMS + lane * 8;
    float* dst = nm + (size_t)row * DIMS + lane * 8;
    #pragma unroll
    for (int h = 0; h < 2; ++h) {
        float4 a = *(const float4*)(r0 + h * 4);
        float4 b = *(const float4*)(r1 + h * 4);
        float4 c = *(const float4*)(r2 + h * 4);
        float4 d = *(const float4*)(r3 + h * 4);
        float4 o;
        o.x = 0.25f * (a.x + b.x + c.x + d.x);
        o.y = 0.25f * (a.y + b.y + c.y + d.y);
        o.z = 0.25f * (a.z + b.z + c.z + d.z);
        o.w = 0.25f * (a.w + b.w + c.w + d.w);
        *(float4*)(dst + h * 4) = o;
    }
}

__global__ __launch_bounds__(256) void conv_kernel(
    const float* __restrict__ query, const float* __restrict__ nm,
    const float* __restrict__ fw, const float* __restrict__ fb,
    float* __restrict__ out)
{
    __shared__ float red[256];
    int pix = blockIdx.x, t = threadIdx.x;
    int i = pix / 28, j = pix % 28;
    float acc = 0.f;
    for (int c = t; c < 1024; c += 256) {
        const float* wrow = fw + c * 9;
        for (int di = 0; di < 3; ++di) {
            int h = i + di - 1;
            if (h < 0 || h >= 28) continue;
            for (int dj = 0; dj < 3; ++dj) {
                int w = j + dj - 1;
                if (w < 0 || w >= 28) continue;
                int n = h * 28 + w;
                float x = (c < 512) ? query[(size_t)n * 512 + c]
                                    : nm[(size_t)n * 512 + (c - 512)];
                acc += x * wrow[di * 3 + dj];
            }
        }
    }
    red[t] = acc;
    __syncthreads();
    for (int s = 128; s; s >>= 1) {
        if (t < s) red[t] += red[t + s];
        __syncthreads();
    }
    if (t == 0) out[pix] = red[0] + fb[0];
}

extern "C" void kernel_launch(void* const* d_in, const int* in_sizes, int n_in,
                              void* d_out, int out_size, void* d_ws, size_t ws_size,
                              hipStream_t stream)
{
    const float* query = (const float*)d_in[0];
    const float* bank  = (const float*)d_in[1];
    const float* fw    = (const float*)d_in[2];
    const float* fb    = (const float*)d_in[3];
    float* out = (float*)d_out;

    char* ws = (char*)d_ws;
    char*  qb8p = ws;                                      // 13*33792     =   439296 B
    uint2* cand = (uint2*)(ws + 439296);                   // 2048*832*8   = 13631488 B
    float* nm   = (float*)(ws + 439296 + 13631488);        // 784*512*4    =  1605632 B

    prep_query<<<208, 256, 0, stream>>>(query, qb8p);
    score_kernel<<<256, 512, 0, stream>>>(bank, qb8p, cand);
    merge_kernel<<<NQ / 4, 256, 0, stream>>>(query, bank, cand, nm);
    conv_kernel<<<NQ, 256, 0, stream>>>(query, nm, fw, fb, out);
}